// Round 10
// baseline (137.559 us; speedup 1.0000x reference)
//
#include <hip/hip_runtime.h>

constexpr float ALPHA = 0.001f;
constexpr float BETA  = 0.001f;
constexpr int R   = 64;
constexpr int S   = 3;
constexpr int PFW = R * (1 + 2 * S); // 448 floats per pF row
constexpr int BSH  = 7;              // 128 pF rows/bucket
constexpr int MAXB = 800;            // >= 782 buckets
constexpr int SBLK = 256;            // scatter block count

__device__ __forceinline__ float bfhi(unsigned u) {
    union { unsigned u; float f; } c; c.u = u & 0xffff0000u; return c.f;
}
__device__ __forceinline__ float bflo(unsigned u) {
    union { unsigned u; float f; } c; c.u = u << 16; return c.f;
}

// ---- hist: LDS-aggregated ----
__global__ __launch_bounds__(256) void hist_kernel(const int* __restrict__ ijk, int B,
                                                   int chunk, int nb, int* __restrict__ hist) {
    __shared__ int lh[MAXB];
    for (int t = threadIdx.x; t < nb; t += blockDim.x) lh[t] = 0;
    __syncthreads();
    const int lo = blockIdx.x * chunk, hi = min(B, lo + chunk);
    for (int idx = lo + threadIdx.x; idx < hi; idx += blockDim.x)
        atomicAdd(&lh[ijk[3 * idx] >> BSH], 1);
    __syncthreads();
    for (int t = threadIdx.x; t < nb; t += blockDim.x)
        if (lh[t]) atomicAdd(&hist[t], lh[t]);
}

// ---- scan -> cursor (exclusive) ----
__global__ __launch_bounds__(1024) void scan_kernel(const int* __restrict__ hist,
                                                    int* __restrict__ cursor, int nb) {
    __shared__ int buf[1024];
    int t = threadIdx.x;
    int own = (t < nb) ? hist[t] : 0;
    buf[t] = own;
    __syncthreads();
    for (int d = 1; d < 1024; d <<= 1) {
        int v = (t >= d) ? buf[t - d] : 0;
        __syncthreads();
        buf[t] += v;
        __syncthreads();
    }
    if (t < nb) cursor[t] = buf[t] - own;
}

// ---- fused scatter (blocks 0..SBLK-1) + convM (blocks SBLK..) ----
__global__ __launch_bounds__(256) void scatconv_kernel(
    const int* __restrict__ ijk, int B, int chunk, int nb,
    int* __restrict__ cursor, int4* __restrict__ sorted,
    const float* __restrict__ M, uint4* __restrict__ Mb, int n8)
{
    if (blockIdx.x >= SBLK) {
        // convM part: M fp32 -> bf16 (RNE), 8 floats per thread
        const int idx = (blockIdx.x - SBLK) * 256 + threadIdx.x;
        if (idx < n8) {
            const float* src = M + (size_t)idx * 8;
            unsigned w[8];
            #pragma unroll
            for (int t = 0; t < 8; ++t) {
                union { float f; unsigned u; } c;
                c.f = __builtin_nontemporal_load(src + t);
                w[t] = (c.u + 0x7fffu + ((c.u >> 16) & 1u)) >> 16;
            }
            Mb[idx] = make_uint4(w[0] | (w[1] << 16), w[2] | (w[3] << 16),
                                 w[4] | (w[5] << 16), w[6] | (w[7] << 16));
        }
        return;
    }
    __shared__ int cnt[MAXB];
    __shared__ int base[MAXB];
    __shared__ int rnk[MAXB];
    for (int t = threadIdx.x; t < nb; t += blockDim.x) { cnt[t] = 0; rnk[t] = 0; }
    __syncthreads();
    const int lo = blockIdx.x * chunk, hi = min(B, lo + chunk);
    for (int idx = lo + threadIdx.x; idx < hi; idx += blockDim.x)
        atomicAdd(&cnt[ijk[3 * idx] >> BSH], 1);
    __syncthreads();
    for (int t = threadIdx.x; t < nb; t += blockDim.x)
        if (cnt[t]) base[t] = atomicAdd(&cursor[t], cnt[t]);
    __syncthreads();
    for (int idx = lo + threadIdx.x; idx < hi; idx += blockDim.x) {
        const int i = ijk[3 * idx], j = ijk[3 * idx + 1], k = ijk[3 * idx + 2];
        const int bkt = i >> BSH;
        const int p = base[bkt] + atomicAdd(&rnk[bkt], 1);
        sorted[p] = make_int4(i, j, k, idx);
    }
}

// ---- main: 8 lanes per entry, 32 entries/block, bucket-ordered, XCD-chunked.
//      Lane l owns r in [8l, 8l+8). Reduce {p,a0,a1,a2} (3 steps), then
//      h = sum_s a_s * g_s,lane and one 3-step h-reduce (15 DS ops vs 28). ----
__global__ __launch_bounds__(256) void mf8_kernel(
    const float* __restrict__ pF,
    const uint4* __restrict__ Mb,     // bf16 packed, 8 uint4 per row
    const int4*  __restrict__ sorted,
    float* __restrict__ out,
    int B, int nwg)
{
    // bijective XCD-chunked swizzle (m204)
    const int orig = blockIdx.x;
    const int q = nwg >> 3, r = nwg & 7;
    const int xcd = orig & 7;
    const int wgid = (xcd < r ? xcd * (q + 1) : r * (q + 1) + (xcd - r) * q) + (orig >> 3);

    const int sub = threadIdx.x & 7;
    const long pos = (long)wgid * 32 + (threadIdx.x >> 3);
    if (pos >= B) return;

    const int4 s = sorted[pos];
    const int kc = (s.z < 0) ? 0 : s.z;

    const float4* pFi = reinterpret_cast<const float4*>(pF + (size_t)s.x * PFW);

    // all loads issued up front
    const uint4 uj = Mb[(size_t)s.y * 8 + sub];
    const uint4 uk = Mb[(size_t)kc  * 8 + sub];
    const float4 pi0 = pFi[2 * sub], pi1 = pFi[2 * sub + 1];
    const float4 v0 = pFi[16 + 6 * sub + 0], v1 = pFi[16 + 6 * sub + 1];
    const float4 v2 = pFi[16 + 6 * sub + 2], v3 = pFi[16 + 6 * sub + 3];
    const float4 v4 = pFi[16 + 6 * sub + 4], v5 = pFi[16 + 6 * sub + 5];
    const float4 w0 = pFi[64 + 6 * sub + 0], w1 = pFi[64 + 6 * sub + 1];
    const float4 w2 = pFi[64 + 6 * sub + 2], w3 = pFi[64 + 6 * sub + 3];
    const float4 w4 = pFi[64 + 6 * sub + 4], w5 = pFi[64 + 6 * sub + 5];

    const float mj0 = bflo(uj.x), mj1 = bfhi(uj.x), mj2 = bflo(uj.y), mj3 = bfhi(uj.y);
    const float mj4 = bflo(uj.z), mj5 = bfhi(uj.z), mj6 = bflo(uj.w), mj7 = bfhi(uj.w);
    const float mk0 = bflo(uk.x), mk1 = bfhi(uk.x), mk2 = bflo(uk.y), mk3 = bfhi(uk.y);
    const float mk4 = bflo(uk.z), mk5 = bfhi(uk.z), mk6 = bflo(uk.w), mk7 = bfhi(uk.w);

    float p = pi0.x * mj0 + pi0.y * mj1 + pi0.z * mj2 + pi0.w * mj3
            + pi1.x * mj4 + pi1.y * mj5 + pi1.z * mj6 + pi1.w * mj7;

    // Vs[r][s], flat c = 3q+s over 24 floats (q=0..7): s=0 -> c=0,3,..,21
    float a0 = v0.x * mj0 + v0.w * mj1 + v1.z * mj2 + v2.y * mj3
             + v3.x * mj4 + v3.w * mj5 + v4.z * mj6 + v5.y * mj7;
    float a1 = v0.y * mj0 + v1.x * mj1 + v1.w * mj2 + v2.z * mj3
             + v3.y * mj4 + v4.x * mj5 + v4.w * mj6 + v5.z * mj7;
    float a2 = v0.z * mj0 + v1.y * mj1 + v2.x * mj2 + v2.w * mj3
             + v3.z * mj4 + v4.y * mj5 + v5.x * mj6 + v5.w * mj7;

    float g0 = w0.x * mk0 + w0.w * mk1 + w1.z * mk2 + w2.y * mk3
             + w3.x * mk4 + w3.w * mk5 + w4.z * mk6 + w5.y * mk7;
    float g1 = w0.y * mk0 + w1.x * mk1 + w1.w * mk2 + w2.z * mk3
             + w3.y * mk4 + w4.x * mk5 + w4.w * mk6 + w5.z * mk7;
    float g2 = w0.z * mk0 + w1.y * mk1 + w2.x * mk2 + w2.w * mk3
             + w3.z * mk4 + w4.y * mk5 + w5.x * mk6 + w5.w * mk7;

    // reduce p, a0..a2 over the 8-lane group (xor 4,2,1 stays in-group)
    #pragma unroll
    for (int off = 4; off >= 1; off >>= 1) {
        p  += __shfl_xor(p,  off);
        a0 += __shfl_xor(a0, off);
        a1 += __shfl_xor(a1, off);
        a2 += __shfl_xor(a2, off);
    }
    // a_s now uniform across the group: sum_l a_s*g_s,l = a_s * g_s
    float h = a0 * g0 + a1 * g1 + a2 * g2;
    #pragma unroll
    for (int off = 4; off >= 1; off >>= 1)
        h += __shfl_xor(h, off);

    if (sub == 0) {
        const float mfm = (s.z != -1) ? (BETA * BETA) * h : 0.0f;
        out[s.w] = ALPHA * p + mfm;
    }
}

// ---- fallback main (round-5 proven, fp32 M, identity order) ----
__global__ __launch_bounds__(256) void mf_if_kernel(
    const float* __restrict__ pF,
    const float* __restrict__ M,
    const int*   __restrict__ ijk,
    float* __restrict__ out,
    int B)
{
    const int sub = threadIdx.x & 15;
    const long pos = (long)blockIdx.x * 16 + (threadIdx.x >> 4);
    if (pos >= B) return;

    const int i = ijk[3 * pos], j = ijk[3 * pos + 1], k = ijk[3 * pos + 2];
    const int kc = (k < 0) ? 0 : k;

    const float4* pFi = reinterpret_cast<const float4*>(pF + (size_t)i * PFW);
    const float4 mj = reinterpret_cast<const float4*>(M + (size_t)j  * R)[sub];
    const float4 mk = reinterpret_cast<const float4*>(M + (size_t)kc * R)[sub];

    const float4 pi = pFi[sub];
    float p = pi.x * mj.x + pi.y * mj.y + pi.z * mj.z + pi.w * mj.w;
    const float4 v0 = pFi[16 + 3 * sub], v1 = pFi[17 + 3 * sub], v2 = pFi[18 + 3 * sub];
    float a0 = v0.x * mj.x + v0.w * mj.y + v1.z * mj.z + v2.y * mj.w;
    float a1 = v0.y * mj.x + v1.x * mj.y + v1.w * mj.z + v2.z * mj.w;
    float a2 = v0.z * mj.x + v1.y * mj.y + v2.x * mj.z + v2.w * mj.w;
    const float4 w0 = pFi[64 + 3 * sub], w1 = pFi[65 + 3 * sub], w2 = pFi[66 + 3 * sub];
    float g0 = w0.x * mk.x + w0.w * mk.y + w1.z * mk.z + w2.y * mk.w;
    float g1 = w0.y * mk.x + w1.x * mk.y + w1.w * mk.z + w2.z * mk.w;
    float g2 = w0.z * mk.x + w1.y * mk.y + w2.x * mk.z + w2.w * mk.w;

    #pragma unroll
    for (int off = 8; off >= 1; off >>= 1) {
        p  += __shfl_xor(p,  off);
        a0 += __shfl_xor(a0, off); a1 += __shfl_xor(a1, off); a2 += __shfl_xor(a2, off);
        g0 += __shfl_xor(g0, off); g1 += __shfl_xor(g1, off); g2 += __shfl_xor(g2, off);
    }
    if (sub == 0) {
        const float mfm = (k != -1) ? (BETA * BETA) * (a0 * g0 + a1 * g1 + a2 * g2) : 0.0f;
        out[pos] = ALPHA * p + mfm;
    }
}

extern "C" void kernel_launch(void* const* d_in, const int* in_sizes, int n_in,
                              void* d_out, int out_size, void* d_ws, size_t ws_size,
                              hipStream_t stream) {
    const float* pF  = (const float*)d_in[0];
    const float* M   = (const float*)d_in[1];
    const int*   ijk = (const int*)d_in[2];
    float* out = (float*)d_out;

    const int B   = in_sizes[2] / 3;     // 500000
    const int N_P = in_sizes[0] / PFW;   // 100000
    const int N_M = in_sizes[1] / R;     // 100000
    const int nb  = (N_P + (1 << BSH) - 1) >> BSH; // 782

    // ws: [0]hist[1024] [4K]cursor[1024] | [16K]sorted int4[B] | Mb bf16[N_M*R]
    const size_t sorted_off = 16 * 1024;
    const size_t mb_off     = sorted_off + (size_t)B * sizeof(int4);
    const size_t need_full  = mb_off + (size_t)N_M * R * 2;

    if (nb <= MAXB && ws_size >= need_full) {
        int*   hist   = (int*)d_ws;
        int*   cursor = (int*)((char*)d_ws + 4096);
        int4*  sorted = (int4*)((char*)d_ws + sorted_off);
        uint4* Mb     = (uint4*)((char*)d_ws + mb_off);
        const int chunk = (B + SBLK - 1) / SBLK;
        const int n8 = N_M * R / 8;
        const int convBlocks = (n8 + 255) / 256;

        hipMemsetAsync(d_ws, 0, 8192, stream);  // hist + cursor
        hist_kernel<<<SBLK, 256, 0, stream>>>(ijk, B, chunk, nb, hist);
        scan_kernel<<<1, 1024, 0, stream>>>(hist, cursor, nb);
        scatconv_kernel<<<SBLK + convBlocks, 256, 0, stream>>>(
            ijk, B, chunk, nb, cursor, sorted, M, Mb, n8);

        const int nwg = (B + 31) / 32;   // 32 entries per 256-thread block
        mf8_kernel<<<nwg, 256, 0, stream>>>(pF, Mb, sorted, out, B, nwg);
    } else {
        mf_if_kernel<<<(B + 15) / 16, 256, 0, stream>>>(pF, M, ijk, out, B);
    }
}

// Round 11
// 91.286 us; speedup vs baseline: 1.5069x; 1.5069x over previous
//
#include <hip/hip_runtime.h>

constexpr float ALPHA = 0.001f;
constexpr float BETA  = 0.001f;
constexpr int R   = 64;
constexpr int S   = 3;
constexpr int PFW = R * (1 + 2 * S); // 448 floats per pF row
constexpr int BSH  = 7;              // 128 pF rows/bucket
constexpr int MAXB = 800;            // >= 782 buckets
constexpr int SBLK = 256;            // scatter block count

__device__ __forceinline__ float bfhi(unsigned u) {
    union { unsigned u; float f; } c; c.u = u & 0xffff0000u; return c.f;
}
__device__ __forceinline__ float bflo(unsigned u) {
    union { unsigned u; float f; } c; c.u = u << 16; return c.f;
}

// ---- hist: LDS-aggregated ----
__global__ __launch_bounds__(256) void hist_kernel(const int* __restrict__ ijk, int B,
                                                   int chunk, int nb, int* __restrict__ hist) {
    __shared__ int lh[MAXB];
    for (int t = threadIdx.x; t < nb; t += blockDim.x) lh[t] = 0;
    __syncthreads();
    const int lo = blockIdx.x * chunk, hi = min(B, lo + chunk);
    for (int idx = lo + threadIdx.x; idx < hi; idx += blockDim.x)
        atomicAdd(&lh[ijk[3 * idx] >> BSH], 1);
    __syncthreads();
    for (int t = threadIdx.x; t < nb; t += blockDim.x)
        if (lh[t]) atomicAdd(&hist[t], lh[t]);
}

// ---- scan -> cursor (exclusive) ----
__global__ __launch_bounds__(1024) void scan_kernel(const int* __restrict__ hist,
                                                    int* __restrict__ cursor, int nb) {
    __shared__ int buf[1024];
    int t = threadIdx.x;
    int own = (t < nb) ? hist[t] : 0;
    buf[t] = own;
    __syncthreads();
    for (int d = 1; d < 1024; d <<= 1) {
        int v = (t >= d) ? buf[t - d] : 0;
        __syncthreads();
        buf[t] += v;
        __syncthreads();
    }
    if (t < nb) cursor[t] = buf[t] - own;
}

// ---- fused scatter (blocks 0..SBLK-1) + convM (blocks SBLK..) ----
__global__ __launch_bounds__(256) void scatconv_kernel(
    const int* __restrict__ ijk, int B, int chunk, int nb,
    int* __restrict__ cursor, int4* __restrict__ sorted,
    const float* __restrict__ M, uint4* __restrict__ Mb, int n8)
{
    if (blockIdx.x >= SBLK) {
        const int idx = (blockIdx.x - SBLK) * 256 + threadIdx.x;
        if (idx < n8) {
            const float* src = M + (size_t)idx * 8;
            unsigned w[8];
            #pragma unroll
            for (int t = 0; t < 8; ++t) {
                union { float f; unsigned u; } c;
                c.f = __builtin_nontemporal_load(src + t);
                w[t] = (c.u + 0x7fffu + ((c.u >> 16) & 1u)) >> 16;
            }
            Mb[idx] = make_uint4(w[0] | (w[1] << 16), w[2] | (w[3] << 16),
                                 w[4] | (w[5] << 16), w[6] | (w[7] << 16));
        }
        return;
    }
    __shared__ int cnt[MAXB];
    __shared__ int base[MAXB];
    __shared__ int rnk[MAXB];
    for (int t = threadIdx.x; t < nb; t += blockDim.x) { cnt[t] = 0; rnk[t] = 0; }
    __syncthreads();
    const int lo = blockIdx.x * chunk, hi = min(B, lo + chunk);
    for (int idx = lo + threadIdx.x; idx < hi; idx += blockDim.x)
        atomicAdd(&cnt[ijk[3 * idx] >> BSH], 1);
    __syncthreads();
    for (int t = threadIdx.x; t < nb; t += blockDim.x)
        if (cnt[t]) base[t] = atomicAdd(&cursor[t], cnt[t]);
    __syncthreads();
    for (int idx = lo + threadIdx.x; idx < hi; idx += blockDim.x) {
        const int i = ijk[3 * idx], j = ijk[3 * idx + 1], k = ijk[3 * idx + 2];
        const int bkt = i >> BSH;
        const int p = base[bkt] + atomicAdd(&rnk[bkt], 1);
        sorted[p] = make_int4(i, j, k, idx);
    }
}

// ---- main: 16 lanes/entry, CONTIGUOUS pF loads (7 x 256B, full line coverage).
//      M rows staged f32 in LDS; per-lane M gathers at thread-constant indices;
//      s-index rotation handled by rotated accumulators (compile-time t-map). ----
__global__ __launch_bounds__(256) void mfc_kernel(
    const float* __restrict__ pF,
    const uint2* __restrict__ Mb,     // bf16 packed, 16 uint2 per row
    const int4*  __restrict__ sorted,
    float* __restrict__ out,
    int B, int nwg)
{
    __shared__ float MjS[16][64];
    __shared__ float MkS[16][64];

    // bijective XCD-chunked swizzle (m204)
    const int orig = blockIdx.x;
    const int q = nwg >> 3, r = nwg & 7;
    const int xcd = orig & 7;
    const int wgid = (xcd < r ? xcd * (q + 1) : r * (q + 1) + (xcd - r) * q) + (orig >> 3);

    const int sub = threadIdx.x & 15;
    const int g   = threadIdx.x >> 4;
    const long pos0 = (long)wgid * 16 + g;
    const bool act = pos0 < B;
    const long pos = act ? pos0 : (long)(B - 1);   // clamp: no early return (barrier)

    const int4 s = sorted[pos];
    const int kc = (s.z < 0) ? 0 : s.z;

    // M loads: 128B contiguous per group (2 lines each)
    const uint2 uj = Mb[(size_t)s.y * 16 + sub];
    const uint2 uk = Mb[(size_t)kc  * 16 + sub];
    const float4 mjv = make_float4(bflo(uj.x), bfhi(uj.x), bflo(uj.y), bfhi(uj.y));
    const float4 mkv = make_float4(bflo(uk.x), bfhi(uk.x), bflo(uk.y), bfhi(uk.y));

    // pF loads: 7 contiguous 256B instructions -> 28 line-requests, each line once
    const float4* pFi = reinterpret_cast<const float4*>(pF + (size_t)s.x * PFW);
    const float4 pi = pFi[sub];
    const float4 vA = pFi[16 + sub], vB = pFi[32 + sub], vC = pFi[48 + sub];
    const float4 wA = pFi[64 + sub], wB = pFi[80 + sub], wC = pFi[96 + sub];

    // stage M rows (f32) to LDS; group-private region, but barrier for safety
    *reinterpret_cast<float4*>(&MjS[g][4 * sub]) = mjv;
    *reinterpret_cast<float4*>(&MkS[g][4 * sub]) = mkv;
    __syncthreads();

    // thread-constant gather indices.
    // Lane holds Vs flats c = {4sub+d, 64+4sub+d, 128+4sub+d}, r = c/3, s = c%3.
    const int rA = (4 * sub) / 3;          const int eA = sub % 3;
    const int rB = 21 + (4 * sub + 1) / 3; const int eB = (sub + 1) % 3;
    const int rC = 42 + (4 * sub + 2) / 3; const int eC = (sub + 2) % 3;

    const float mA0 = MjS[g][rA], mA1 = MjS[g][rA + 1];
    const float mB0 = MjS[g][rB], mB1 = MjS[g][rB + 1];
    const float mC0 = MjS[g][rC], mC1 = MjS[g][rC + 1];
    const float nA0 = MkS[g][rA], nA1 = MkS[g][rA + 1];
    const float nB0 = MkS[g][rB], nB1 = MkS[g][rB + 1];
    const float nC0 = MkS[g][rC], nC1 = MkS[g][rC + 1];

    float p = pi.x * mjv.x + pi.y * mjv.y + pi.z * mjv.z + pi.w * mjv.w;

    // rotated accumulators: ah[t] = a_{(sigma+t)%3}, sigma = sub%3.
    // Segment t-maps (d=0..3): A->(0,1,2,0), B->(1,2,0,1), C->(2,0,1,2).
    // r increments within a segment when (e+d)>=3; d=0 always lo, d=3 always hi.
    float ah0 = vA.x * mA0 + vA.w * mA1;
    float ah1 = vA.y * (eA >= 2 ? mA1 : mA0);
    float ah2 = vA.z * (eA >= 1 ? mA1 : mA0);
    ah1 += vB.x * mB0 + vB.w * mB1;
    ah2 += vB.y * (eB >= 2 ? mB1 : mB0);
    ah0 += vB.z * (eB >= 1 ? mB1 : mB0);
    ah2 += vC.x * mC0 + vC.w * mC1;
    ah0 += vC.y * (eC >= 2 ? mC1 : mC0);
    ah1 += vC.z * (eC >= 1 ? mC1 : mC0);

    float gh0 = wA.x * nA0 + wA.w * nA1;
    float gh1 = wA.y * (eA >= 2 ? nA1 : nA0);
    float gh2 = wA.z * (eA >= 1 ? nA1 : nA0);
    gh1 += wB.x * nB0 + wB.w * nB1;
    gh2 += wB.y * (eB >= 2 ? nB1 : nB0);
    gh0 += wB.z * (eB >= 1 ? nB1 : nB0);
    gh2 += wC.x * nC0 + wC.w * nC1;
    gh0 += wC.y * (eC >= 2 ? nC1 : nC0);
    gh1 += wC.z * (eC >= 1 ? nC1 : nC0);

    // un-rotate a for the cross-lane reduce: a_s = ah[(s - sigma) mod 3]
    const int sg = sub % 3;
    float a0 = sg == 0 ? ah0 : (sg == 1 ? ah2 : ah1);
    float a1 = sg == 0 ? ah1 : (sg == 1 ? ah0 : ah2);
    float a2 = sg == 0 ? ah2 : (sg == 1 ? ah1 : ah0);

    #pragma unroll
    for (int off = 8; off >= 1; off >>= 1) {
        p  += __shfl_xor(p,  off);
        a0 += __shfl_xor(a0, off);
        a1 += __shfl_xor(a1, off);
        a2 += __shfl_xor(a2, off);
    }
    // a now uniform; re-rotate to pair with this lane's rotated gh
    const float ar0 = sg == 0 ? a0 : (sg == 1 ? a1 : a2);
    const float ar1 = sg == 0 ? a1 : (sg == 1 ? a2 : a0);
    const float ar2 = sg == 0 ? a2 : (sg == 1 ? a0 : a1);
    float h = ar0 * gh0 + ar1 * gh1 + ar2 * gh2;
    #pragma unroll
    for (int off = 8; off >= 1; off >>= 1)
        h += __shfl_xor(h, off);

    if (act && sub == 0) {
        const float mfm = (s.z != -1) ? (BETA * BETA) * h : 0.0f;
        out[s.w] = ALPHA * p + mfm;
    }
}

// ---- fallback main (round-5 proven, fp32 M, identity order) ----
__global__ __launch_bounds__(256) void mf_if_kernel(
    const float* __restrict__ pF,
    const float* __restrict__ M,
    const int*   __restrict__ ijk,
    float* __restrict__ out,
    int B)
{
    const int sub = threadIdx.x & 15;
    const long pos = (long)blockIdx.x * 16 + (threadIdx.x >> 4);
    if (pos >= B) return;

    const int i = ijk[3 * pos], j = ijk[3 * pos + 1], k = ijk[3 * pos + 2];
    const int kc = (k < 0) ? 0 : k;

    const float4* pFi = reinterpret_cast<const float4*>(pF + (size_t)i * PFW);
    const float4 mj = reinterpret_cast<const float4*>(M + (size_t)j  * R)[sub];
    const float4 mk = reinterpret_cast<const float4*>(M + (size_t)kc * R)[sub];

    const float4 pi = pFi[sub];
    float p = pi.x * mj.x + pi.y * mj.y + pi.z * mj.z + pi.w * mj.w;
    const float4 v0 = pFi[16 + 3 * sub], v1 = pFi[17 + 3 * sub], v2 = pFi[18 + 3 * sub];
    float a0 = v0.x * mj.x + v0.w * mj.y + v1.z * mj.z + v2.y * mj.w;
    float a1 = v0.y * mj.x + v1.x * mj.y + v1.w * mj.z + v2.z * mj.w;
    float a2 = v0.z * mj.x + v1.y * mj.y + v2.x * mj.z + v2.w * mj.w;
    const float4 w0 = pFi[64 + 3 * sub], w1 = pFi[65 + 3 * sub], w2 = pFi[66 + 3 * sub];
    float g0 = w0.x * mk.x + w0.w * mk.y + w1.z * mk.z + w2.y * mk.w;
    float g1 = w0.y * mk.x + w1.x * mk.y + w1.w * mk.z + w2.z * mk.w;
    float g2 = w0.z * mk.x + w1.y * mk.y + w2.x * mk.z + w2.w * mk.w;

    #pragma unroll
    for (int off = 8; off >= 1; off >>= 1) {
        p  += __shfl_xor(p,  off);
        a0 += __shfl_xor(a0, off); a1 += __shfl_xor(a1, off); a2 += __shfl_xor(a2, off);
        g0 += __shfl_xor(g0, off); g1 += __shfl_xor(g1, off); g2 += __shfl_xor(g2, off);
    }
    if (sub == 0) {
        const float mfm = (k != -1) ? (BETA * BETA) * (a0 * g0 + a1 * g1 + a2 * g2) : 0.0f;
        out[pos] = ALPHA * p + mfm;
    }
}

extern "C" void kernel_launch(void* const* d_in, const int* in_sizes, int n_in,
                              void* d_out, int out_size, void* d_ws, size_t ws_size,
                              hipStream_t stream) {
    const float* pF  = (const float*)d_in[0];
    const float* M   = (const float*)d_in[1];
    const int*   ijk = (const int*)d_in[2];
    float* out = (float*)d_out;

    const int B   = in_sizes[2] / 3;     // 500000
    const int N_P = in_sizes[0] / PFW;   // 100000
    const int N_M = in_sizes[1] / R;     // 100000
    const int nb  = (N_P + (1 << BSH) - 1) >> BSH; // 782

    // ws: [0]hist[1024] [4K]cursor[1024] | [16K]sorted int4[B] | Mb bf16[N_M*R]
    const size_t sorted_off = 16 * 1024;
    const size_t mb_off     = sorted_off + (size_t)B * sizeof(int4);
    const size_t need_full  = mb_off + (size_t)N_M * R * 2;

    if (nb <= MAXB && ws_size >= need_full) {
        int*   hist   = (int*)d_ws;
        int*   cursor = (int*)((char*)d_ws + 4096);
        int4*  sorted = (int4*)((char*)d_ws + sorted_off);
        uint4* Mb     = (uint4*)((char*)d_ws + mb_off);
        const int chunk = (B + SBLK - 1) / SBLK;
        const int n8 = N_M * R / 8;
        const int convBlocks = (n8 + 255) / 256;

        hipMemsetAsync(d_ws, 0, 8192, stream);  // hist + cursor
        hist_kernel<<<SBLK, 256, 0, stream>>>(ijk, B, chunk, nb, hist);
        scan_kernel<<<1, 1024, 0, stream>>>(hist, cursor, nb);
        scatconv_kernel<<<SBLK + convBlocks, 256, 0, stream>>>(
            ijk, B, chunk, nb, cursor, sorted, M, Mb, n8);

        const int nwg = (B + 15) / 16;   // 16 entries per 256-thread block
        mfc_kernel<<<nwg, 256, 0, stream>>>(pF, (const uint2*)Mb, sorted, out, B, nwg);
    } else {
        mf_if_kernel<<<(B + 15) / 16, 256, 0, stream>>>(pF, M, ijk, out, B);
    }
}